// Round 11
// baseline (87.589 us; speedup 1.0000x reference)
//
#include <hip/hip_runtime.h>

#define NG   2000
#define NPG  50
#define EPG  800
#define F0   64
#define FH   128
#define FP   512

typedef __attribute__((ext_vector_type(8))) short  short8;
typedef __attribute__((ext_vector_type(8))) __bf16 bf16x8;
typedef __attribute__((ext_vector_type(4))) float  f32x4;
typedef unsigned short u16;
typedef unsigned int   u32;

__device__ inline u16 bf16_rne(float x) {
    u32 u = __builtin_bit_cast(u32, x);
    u += 0x7fffu + ((u >> 16) & 1u);
    return (u16)(u >> 16);
}
__device__ inline float bf16f(u16 h) {
    u32 u = ((u32)h) << 16;
    return __builtin_bit_cast(float, u);
}
// HW packed convert: dst.b16[0] = bf16(src0), dst.b16[1] = bf16(src1)
__device__ inline u32 cvtpk2(float lo, float hi) {
    u32 r;
    asm("v_cvt_pk_bf16_f32 %0, %1, %2" : "=v"(r) : "v"(lo), "v"(hi));
    return r;
}
__device__ inline void split2(float v0, float v1, u32& hp, u32& lp) {
    hp = cvtpk2(v0, v1);
    float h0 = __builtin_bit_cast(float, hp << 16);
    float h1 = __builtin_bit_cast(float, hp & 0xffff0000u);
    lp = cvtpk2(v0 - h0, v1 - h1);
}
__device__ inline f32x4 mfma16(short8 a, short8 b, f32x4 c) {
    return __builtin_amdgcn_mfma_f32_16x16x32_bf16(
        __builtin_bit_cast(bf16x8, a), __builtin_bit_cast(bf16x8, b), c, 0, 0, 0);
}

// swizzled LDS index helpers (u16 units; XOR 16B-chunk id with row bits)
__device__ inline int xb_idx(int row, int col)  { return row * 128 + (col ^ ((row  & 7) << 3)); }
__device__ inline int tb_idx(int feat, int node){ return feat * 64 + (node ^ ((feat & 7) << 3)); }
__device__ inline int ab_idx(int d, int s)      { return d * 64 + (s ^ ((d  & 7) << 3)); }

// ---------- one-time W split+pack into MFMA B-fragment layout ----------
__global__ __launch_bounds__(256) void pack_w(
    const float* __restrict__ W0, const float* __restrict__ W1,
    const float* __restrict__ W2, u16* __restrict__ WpH, u16* __restrict__ WpL)
{
    int t = blockIdx.x * 256 + threadIdx.x;
    if (t >= 80 * 64) return;
    int fid = t >> 6, lane = t & 63;
    const float* W; int nsub, kstep;
    if (fid < 16)      { W = W0; int r = fid;      nsub = r >> 1; kstep = r & 1; }
    else if (fid < 48) { W = W1; int r = fid - 16; nsub = r >> 2; kstep = r & 3; }
    else               { W = W2; int r = fid - 48; nsub = r >> 2; kstep = r & 3; }
    int n  = nsub * 16 + (lane & 15);
    int kb = kstep * 32 + (lane >> 4) * 8;
    size_t off = (size_t)fid * 512 + (size_t)lane * 8;
#pragma unroll
    for (int i = 0; i < 8; ++i) {
        float v = W[(size_t)(kb + i) * FH + n];
        u16 h = bf16_rne(v);
        WpH[off + i] = h;
        WpL[off + i] = bf16_rne(v - bf16f(h));
    }
}

// ---------- MFMA1: T^T[feat][node] = ((X @ W) * nout_row)^T ----------
// wave = nsg; 3 independent accumulator chains (depth KST instead of 3*KST).
template<int KST>
__device__ void mfma1_fn(const u16* __restrict__ WpH, const u16* __restrict__ WpL,
                         int fid0, const u16* XbH, const u16* XbL,
                         u16* TbH, u16* TbL, const float* nout64,
                         int lane, int nsg)
{
    const int l15 = lane & 15, lk = lane >> 4;
    const int feat = nsg * 16 + l15;
    short8 bh[KST], bl[KST];
#pragma unroll
    for (int ks = 0; ks < KST; ++ks) {
        size_t off = (size_t)(fid0 + nsg * KST + ks) * 512 + (size_t)lane * 8;
        bh[ks] = *(const short8*)(WpH + off);
        bl[ks] = *(const short8*)(WpL + off);
    }
#pragma unroll
    for (int ms = 0; ms < 4; ++ms) {
        const int arow = ms * 16 + l15;
        f32x4 aA = {0.f, 0.f, 0.f, 0.f}, aB = aA, aC = aA;
#pragma unroll
        for (int ks = 0; ks < KST; ++ks) {
            int c0 = ks * 32 + lk * 8;
            short8 ah = *(const short8*)&XbH[xb_idx(arow, c0)];
            short8 al = *(const short8*)&XbL[xb_idx(arow, c0)];
            aA = mfma16(ah, bh[ks], aA);     // 3 independent chains
            aB = mfma16(ah, bl[ks], aB);
            aC = mfma16(al, bh[ks], aC);
        }
        f32x4 acc = aA + aB + aC;
        const int nb = ms * 16 + lk * 4;
        float4 nq = *(const float4*)&nout64[nb];   // 0 for nodes >= NPG
        u32 h01, l01, h23, l23;
        split2(acc[0] * nq.x, acc[1] * nq.y, h01, l01);
        split2(acc[2] * nq.z, acc[3] * nq.w, h23, l23);
        int idx = tb_idx(feat, nb);
        *(uint2*)&TbH[idx] = make_uint2(h01, h23);
        *(uint2*)&TbL[idx] = make_uint2(l01, l23);
    }
}

// ---------- MFMA2: X' = relu((C @ T) * nin_row + b) ; C in registers ----------
template<bool LAST>
__device__ void mfma2_fn(const float* __restrict__ bias, short8 a0, short8 a1,
                         const u16* TbH, const u16* TbL,
                         u16* XbH, u16* XbL, float* pool, float4 ninq,
                         int lane, int mstrip, int nhalf)
{
    const int l15 = lane & 15, lk = lane >> 4;
    const int nb = mstrip * 16 + lk * 4;
#pragma unroll
    for (int ns = 0; ns < 4; ++ns) {
        const int nsg  = nhalf * 4 + ns;
        const int feat = nsg * 16 + l15;
        const float bc = bias[feat];
        short8 bh0 = *(const short8*)&TbH[tb_idx(feat, lk * 8)];
        short8 bl0 = *(const short8*)&TbL[tb_idx(feat, lk * 8)];
        short8 bh1 = *(const short8*)&TbH[tb_idx(feat, 32 + lk * 8)];
        short8 bl1 = *(const short8*)&TbL[tb_idx(feat, 32 + lk * 8)];
        f32x4 p0 = {0.f, 0.f, 0.f, 0.f}, p1 = p0;
        p0 = mfma16(a0, bh0, p0);            // 2 independent chains, depth 2
        p1 = mfma16(a1, bh1, p1);
        p0 = mfma16(a0, bl0, p0);
        p1 = mfma16(a1, bl1, p1);
        f32x4 acc = p0 + p1;
        float v0 = (nb + 0 < NPG) ? fmaxf(fmaf(acc[0], ninq.x, bc), 0.f) : 0.f;
        float v1 = (nb + 1 < NPG) ? fmaxf(fmaf(acc[1], ninq.y, bc), 0.f) : 0.f;
        float v2 = (nb + 2 < NPG) ? fmaxf(fmaf(acc[2], ninq.z, bc), 0.f) : 0.f;
        float v3 = (nb + 3 < NPG) ? fmaxf(fmaf(acc[3], ninq.w, bc), 0.f) : 0.f;
        if (LAST) {
            float vs = v0 + v1 + v2 + v3;
            vs += __shfl_xor(vs, 16, 64);
            vs += __shfl_xor(vs, 32, 64);
            if (lane < 16) atomicAdd(&pool[nsg * 16 + lane], vs);
        } else {
            u32 hp01, lp01, hp23, lp23;
            split2(v0, v1, hp01, lp01);
            split2(v2, v3, hp23, lp23);
            XbH[xb_idx(nb + 0, feat)] = (u16)hp01;
            XbH[xb_idx(nb + 1, feat)] = (u16)(hp01 >> 16);
            XbH[xb_idx(nb + 2, feat)] = (u16)hp23;
            XbH[xb_idx(nb + 3, feat)] = (u16)(hp23 >> 16);
            XbL[xb_idx(nb + 0, feat)] = (u16)lp01;
            XbL[xb_idx(nb + 1, feat)] = (u16)(lp01 >> 16);
            XbL[xb_idx(nb + 2, feat)] = (u16)lp23;
            XbL[xb_idx(nb + 3, feat)] = (u16)(lp23 >> 16);
        }
    }
}

// ---------- main fused kernel: one block = one graph ----------
__global__ __launch_bounds__(512, 4) void gcn_fused(
    const float* __restrict__ nf, const int* __restrict__ pair,
    const int* __restrict__ num_nodes,
    const float* __restrict__ b0, const float* __restrict__ b1,
    const float* __restrict__ b2,
    const u16* __restrict__ WpH, const u16* __restrict__ WpL,
    float* __restrict__ means)
{
    __shared__ u16 XbH[64 * 128], XbL[64 * 128];   // X hi/lo [node][feat], swizzled
    __shared__ u16 TbH[128 * 64], TbL[128 * 64];   // T^T hi/lo [feat][node], swizzled
    __shared__ float pool[FH];
    __shared__ int   din[NPG], dout[NPG];
    __shared__ float nin64[64], nout64[64];

    float* cnt = (float*)TbH;   // f32 count scratch aliased over TbH (dead until mfma1-L0)

    const int tid  = threadIdx.x;
    const int g    = blockIdx.x;
    const int base = g * NPG, ebase = g * EPG;
    const int* srcp = pair;
    const int* dstp = pair + (size_t)NG * EPG;

    // ---- init ----
    if (tid < NPG) { din[tid] = 0; dout[tid] = 0; }
    if (tid < FH) pool[tid] = 0.f;
    for (int i = tid; i < 4096; i += 512) cnt[i] = 0.f;
    for (int i = 3200 + tid; i < 4096; i += 512) {   // Xb pad rows 50-63
        ((u32*)XbH)[i] = 0u; ((u32*)XbL)[i] = 0u;
    }
    __syncthreads();

    // ---- single edge pass: degrees + dense count matrix (exact ints in f32) ----
    for (int e = tid; e < EPG; e += 512) {
        int s = srcp[ebase + e] - base, d = dstp[ebase + e] - base;
        atomicAdd(&dout[s], 1);
        atomicAdd(&din [d], 1);
        atomicAdd(&cnt[ab_idx(d, s)], 1.0f);
    }
    // ---- X0 load + hi/lo split ----
    for (int i = tid; i < NPG * 16; i += 512) {
        int n = i >> 4, c4 = (i & 15) * 4;
        float4 v = *(const float4*)(nf + (size_t)(base + n) * F0 + c4);
        u32 h01, l01, h23, l23;
        split2(v.x, v.y, h01, l01);
        split2(v.z, v.w, h23, l23);
        int idx = xb_idx(n, c4);
        *(uint2*)&XbH[idx] = make_uint2(h01, h23);
        *(uint2*)&XbL[idx] = make_uint2(l01, l23);
    }
    __syncthreads();

    // ---- norms (zero-padded) ----
    if (tid < 64) {
        nout64[tid] = (tid < NPG) ? rsqrtf((float)max(dout[tid], 1)) : 0.f;
        nin64 [tid] = (tid < NPG) ? rsqrtf((float)max(din [tid], 1)) : 0.f;
    }

    const int lane   = tid & 63;
    const int wv     = __builtin_amdgcn_readfirstlane(tid >> 6);
    const int mstrip = wv & 3, nhalf = wv >> 2;
    const int l15 = lane & 15, lk = lane >> 4;
    const int arow = mstrip * 16 + l15;

    // ---- per-wave A-fragment: exact counts -> bf16 registers (layer-invariant).
    // Swizzle keeps each 8-float run contiguous; rows >= 50 are naturally zero.
    short8 aReg[2];
#pragma unroll
    for (int ks = 0; ks < 2; ++ks) {
        int sbase = (ks * 32 + lk * 8) ^ ((arow & 7) << 3);
        const float* cp = cnt + arow * 64 + sbase;
        float4 c0 = *(const float4*)cp;
        float4 c1 = *(const float4*)(cp + 4);
        uint4 q = make_uint4(cvtpk2(c0.x, c0.y), cvtpk2(c0.z, c0.w),
                             cvtpk2(c1.x, c1.y), cvtpk2(c1.z, c1.w));
        aReg[ks] = __builtin_bit_cast(short8, q);
    }
    __syncthreads();   // cnt reads done before mfma1 overwrites TbH

    float4 ninq = *(const float4*)&nin64[mstrip * 16 + lk * 4];

    mfma1_fn<2>(WpH, WpL, 0,  XbH, XbL, TbH, TbL, nout64, lane, wv);
    __syncthreads();
    mfma2_fn<false>(b0, aReg[0], aReg[1], TbH, TbL, XbH, XbL, pool, ninq, lane, mstrip, nhalf);
    __syncthreads();
    mfma1_fn<4>(WpH, WpL, 16, XbH, XbL, TbH, TbL, nout64, lane, wv);
    __syncthreads();
    mfma2_fn<false>(b1, aReg[0], aReg[1], TbH, TbL, XbH, XbL, pool, ninq, lane, mstrip, nhalf);
    __syncthreads();
    mfma1_fn<4>(WpH, WpL, 48, XbH, XbL, TbH, TbL, nout64, lane, wv);
    __syncthreads();
    mfma2_fn<true>(b2, aReg[0], aReg[1], TbH, TbL, XbH, XbL, pool, ninq, lane, mstrip, nhalf);
    __syncthreads();

    if (tid < FH) means[(size_t)g * FH + tid] = pool[tid] / (float)num_nodes[g];
}

// ---------------- Kernel 3: MLP head ----------------
__global__ __launch_bounds__(512) void mlp_head(
    const float* __restrict__ means, const float* __restrict__ Wp1,
    const float* __restrict__ bp1,   const float* __restrict__ Wp2,
    const float* __restrict__ bp2,   float* __restrict__ out)
{
    __shared__ float ms[8][FH];
    __shared__ float wred[8][8];
    const int tid = threadIdx.x;
    const int g0  = blockIdx.x * 8;

    for (int i = tid; i < 8 * FH; i += 512)
        ms[i >> 7][i & 127] = means[(size_t)g0 * FH + i];
    __syncthreads();

    const int f = tid;
    float acc[8];
    float bb = bp1[f];
#pragma unroll
    for (int gi = 0; gi < 8; ++gi) acc[gi] = bb;
    for (int k = 0; k < FH; ++k) {
        float w = Wp1[(size_t)k * FP + f];
#pragma unroll
        for (int gi = 0; gi < 8; ++gi) acc[gi] += ms[gi][k] * w;
    }
    float w2 = Wp2[f];
#pragma unroll
    for (int gi = 0; gi < 8; ++gi) {
        float v = fmaxf(acc[gi], 0.f) * w2;
#pragma unroll
        for (int o = 32; o > 0; o >>= 1) v += __shfl_down(v, o, 64);
        if ((tid & 63) == 0) wred[tid >> 6][gi] = v;
    }
    __syncthreads();
    if (tid < 8) {
        float s = 0.f;
#pragma unroll
        for (int w = 0; w < 8; ++w) s += wred[w][tid];
        out[g0 + tid] = s + bp2[0];
    }
}

extern "C" void kernel_launch(void* const* d_in, const int* in_sizes, int n_in,
                              void* d_out, int out_size, void* d_ws, size_t ws_size,
                              hipStream_t stream) {
    const float* nf   = (const float*)d_in[0];
    const int*   pair = (const int*)d_in[2];
    const int*   nn   = (const int*)d_in[3];
    const float* W0  = (const float*)d_in[5];  const float* b0  = (const float*)d_in[6];
    const float* W1  = (const float*)d_in[7];  const float* b1  = (const float*)d_in[8];
    const float* W2  = (const float*)d_in[9];  const float* b2  = (const float*)d_in[10];
    const float* Wp1 = (const float*)d_in[11]; const float* bp1 = (const float*)d_in[12];
    const float* Wp2 = (const float*)d_in[13]; const float* bp2 = (const float*)d_in[14];

    float* means = (float*)d_ws;                                   // 1,024,000 B
    u16*   WpH   = (u16*)((char*)d_ws + (1 << 20));                // 81,920 B
    u16*   WpL   = (u16*)((char*)d_ws + (1 << 20) + 80 * 1024);    // 81,920 B
    float* out   = (float*)d_out;

    hipLaunchKernelGGL(pack_w, dim3(20), dim3(256), 0, stream, W0, W1, W2, WpH, WpL);
    hipLaunchKernelGGL(gcn_fused, dim3(NG), dim3(512), 0, stream,
                       nf, pair, nn, b0, b1, b2, WpH, WpL, means);
    hipLaunchKernelGGL(mlp_head, dim3(NG / 8), dim3(512), 0, stream,
                       means, Wp1, bp1, Wp2, bp2, out);
}